// Round 1
// baseline (1185.642 us; speedup 1.0000x reference)
//
#include <hip/hip_runtime.h>
#include <math.h>

#define FN 512
#define LOGN 9
#define ROWS 16
#define PITCH 513   // complex pitch (pad +1 to break power-of-2 strides across rows)
#define TPB 256
#define NIMG 256
#define NBATCH 8
#define NCH 32
#define NBINS 257

typedef unsigned long long ull;

__device__ __forceinline__ int brev9(int x) { return (int)(__brev((unsigned)x) >> 23); }

__device__ __forceinline__ float2 cmulf(float2 a, float2 b) {
  return make_float2(a.x*b.x - a.y*b.y, a.x*b.y + a.y*b.x);
}

__device__ __forceinline__ void init_tw(float2* tw) {
  if (threadIdx.x < 256) {
    float ang = -6.28318530717958647692f * ((float)threadIdx.x / 512.0f);
    float s, c;
    sincosf(ang, &s, &c);
    tw[threadIdx.x] = make_float2(c, s);
  }
}

// DIF: natural order in -> bit-reversed out. tw[k] = exp(-2*pi*i*k/512)
template<bool INV>
__device__ __forceinline__ void fft_dif(float2 (*lds)[PITCH], const float2* tw) {
  for (int s = LOGN - 1; s >= 0; --s) {
    __syncthreads();
    const int half = 1 << s;
    #pragma unroll
    for (int it = 0; it < (ROWS * (FN/2)) / TPB; ++it) {
      int idx = threadIdx.x + it * TPB;
      int row = idx >> 8;          // 256 butterflies per row
      int b   = idx & 255;
      int i   = b & (half - 1);
      int g   = b >> s;
      int pos = (g << (s + 1)) + i;
      float2 u = lds[row][pos];
      float2 v = lds[row][pos + half];
      float2 w = tw[i << (8 - s)];
      if (INV) w.y = -w.y;
      lds[row][pos] = make_float2(u.x + v.x, u.y + v.y);
      float2 d = make_float2(u.x - v.x, u.y - v.y);
      lds[row][pos + half] = cmulf(d, w);
    }
  }
  __syncthreads();
}

// DIT: bit-reversed order in -> natural order out.
template<bool INV>
__device__ __forceinline__ void fft_dit(float2 (*lds)[PITCH], const float2* tw) {
  for (int s = 0; s < LOGN; ++s) {
    __syncthreads();
    const int half = 1 << s;
    #pragma unroll
    for (int it = 0; it < (ROWS * (FN/2)) / TPB; ++it) {
      int idx = threadIdx.x + it * TPB;
      int row = idx >> 8;
      int b   = idx & 255;
      int i   = b & (half - 1);
      int g   = b >> s;
      int pos = (g << (s + 1)) + i;
      float2 w = tw[i << (8 - s)];
      if (INV) w.y = -w.y;
      float2 t = cmulf(lds[row][pos + half], w);
      float2 u = lds[row][pos];
      lds[row][pos]        = make_float2(u.x + t.x, u.y + t.y);
      lds[row][pos + half] = make_float2(u.x - t.x, u.y - t.y);
    }
  }
  __syncthreads();
}

__device__ __forceinline__ void load_complex(float2 (*lds)[PITCH], const float2* __restrict__ src,
                                             bool bitrev) {
  const float4* __restrict__ s4 = (const float4*)src;
  #pragma unroll
  for (int k = 0; k < 16; ++k) {
    int q = threadIdx.x + k * TPB;   // float4 id: 2 complex each
    float4 v = s4[q];
    int f = q << 1;
    int row = f >> 9;
    int col = f & 511;
    if (bitrev) {
      lds[row][brev9(col)]     = make_float2(v.x, v.y);
      lds[row][brev9(col + 1)] = make_float2(v.z, v.w);
    } else {
      lds[row][col]     = make_float2(v.x, v.y);
      lds[row][col + 1] = make_float2(v.z, v.w);
    }
  }
}

// Transposed store: dst[v(p)][R0 + r] = lds[r][p]; 128B contiguous chunks.
__device__ __forceinline__ void store_transposed(const float2 (*lds)[PITCH], float2* __restrict__ dst,
                                                 int R0, bool bitrev) {
  const int rl2 = threadIdx.x & 7;   // which complex pair of the 16 rows
  const int pg  = threadIdx.x >> 3;  // 32 p positions per iteration
  #pragma unroll
  for (int k = 0; k < 16; ++k) {
    int p  = pg + k * 32;
    int vv = bitrev ? brev9(p) : p;
    float2 a = lds[2 * rl2][p];
    float2 b = lds[2 * rl2 + 1][p];
    float4* d4 = (float4*)(dst + (size_t)vv * FN + R0);
    d4[rl2] = make_float4(a.x, a.y, b.x, b.y);
  }
}

// Pass 1 (and pre-pass): real rows -> forward FFT -> transposed store (natural spectral order).
__global__ __launch_bounds__(TPB) void k_fwd_real(const float* __restrict__ x,
                                                  float2* __restrict__ W,
                                                  int img0, int img_stride) {
  __shared__ float2 lds[ROWS][PITCH];
  __shared__ float2 tw[256];
  init_tw(tw);
  const int li = blockIdx.x >> 5;
  const int R0 = (blockIdx.x & 31) * ROWS;
  const int img = img0 + li * img_stride;
  const float4* __restrict__ s4 = (const float4*)(x + (size_t)img * FN * FN + (size_t)R0 * FN);
  #pragma unroll
  for (int k = 0; k < 8; ++k) {
    int q = threadIdx.x + k * TPB;
    float4 v = s4[q];
    int f = q << 2;
    int row = f >> 9;
    int col = f & 511;
    lds[row][col]     = make_float2(v.x, 0.f);
    lds[row][col + 1] = make_float2(v.y, 0.f);
    lds[row][col + 2] = make_float2(v.z, 0.f);
    lds[row][col + 3] = make_float2(v.w, 0.f);
  }
  fft_dif<false>(lds, tw);
  store_transposed(lds, W + (size_t)li * FN * FN, R0, true /*v=brev(p): natural order out*/);
}

// Pre-pass 2: forward FFT along second axis on channel-0 images; bin |F|^2 into rings (fixed-point, deterministic).
__global__ __launch_bounds__(TPB) void k_ring(const float2* __restrict__ W1p, ull* __restrict__ bins) {
  __shared__ float2 lds[ROWS][PITCH];
  __shared__ float2 tw[256];
  __shared__ ull lbins[NBINS];
  init_tw(tw);
  for (int t = threadIdx.x; t < NBINS; t += TPB) lbins[t] = 0;
  const int li = blockIdx.x >> 5;               // batch 0..7
  const int V0 = (blockIdx.x & 31) * ROWS;
  load_complex(lds, W1p + (size_t)li * FN * FN + (size_t)V0 * FN, false);
  fft_dif<false>(lds, tw);
  #pragma unroll
  for (int k = 0; k < 32; ++k) {
    int idx = threadIdx.x + k * TPB;
    int row = idx >> 9;
    int p   = idx & 511;
    int u = brev9(p);
    int v = V0 + row;
    int cu = (u < 256) ? (u + 1) : (512 - u);
    int cv = (v < 256) ? (v + 1) : (512 - v);
    int s = (cu > cv) ? cu : cv;
    float2 val = lds[row][p];
    float e = val.x * val.x + val.y * val.y;
    ull q = (ull)((double)e * 1048576.0);       // 2^20 fixed point
    atomicAdd(&lbins[s], q);
  }
  __syncthreads();
  for (int t = threadIdx.x; t < NBINS; t += TPB)
    atomicAdd(&bins[(size_t)li * NBINS + t], lbins[t]);
}

__global__ __launch_bounds__(64) void k_cutoff(const ull* __restrict__ bins, int* __restrict__ cut) {
  int b = threadIdx.x;
  if (b >= NBATCH) return;
  double tot = 0.0;
  for (int r = 0; r < NBINS; ++r) tot += (double)bins[b * NBINS + r];
  double target = 0.5 * tot;
  double cum = 0.0;
  int c = 5;
  bool found = false;
  for (int r = 0; r <= 255; ++r) {
    cum += (double)bins[b * NBINS + r];
    if (r >= 1 && !found && cum >= target) { c = r; found = true; }
  }
  cut[b] = c;
}

// Pass 2: forward FFT along second axis -> mask (per-batch cutoff) -> inverse FFT -> transposed store.
__global__ __launch_bounds__(TPB) void k_mask(const float2* __restrict__ Wa, float2* __restrict__ Wb,
                                              const int* __restrict__ cut, int img0) {
  __shared__ float2 lds[ROWS][PITCH];
  __shared__ float2 tw[256];
  init_tw(tw);
  const int li = blockIdx.x >> 5;
  const int V0 = (blockIdx.x & 31) * ROWS;
  const int img = img0 + li;
  const int batch = img >> 5;                   // 32 channels per batch
  load_complex(lds, Wa + (size_t)li * FN * FN + (size_t)V0 * FN, false);
  fft_dif<false>(lds, tw);
  const int cutoff = cut[batch];
  #pragma unroll
  for (int k = 0; k < 32; ++k) {
    int idx = threadIdx.x + k * TPB;
    int row = idx >> 9;
    int p   = idx & 511;
    int u = brev9(p);
    int v = V0 + row;
    int cu = (u < 256) ? (u + 1) : (512 - u);
    int cv = (v < 256) ? (v + 1) : (512 - v);
    int s = (cu > cv) ? cu : cv;
    float m = (s > cutoff) ? (1.0f / 512.0f) : 0.0f;  // fold 1/N of this inverse axis in
    float2 val = lds[row][p];
    lds[row][p] = make_float2(val.x * m, val.y * m);
  }
  fft_dit<true>(lds, tw);
  store_transposed(lds, Wb + (size_t)li * FN * FN, V0, false /*natural*/);
}

// Pass 3: inverse FFT along first axis -> |y|/512 -> direct coalesced store.
__global__ __launch_bounds__(TPB) void k_inv_abs(const float2* __restrict__ Wb, float* __restrict__ out,
                                                 int img0) {
  __shared__ float2 lds[ROWS][PITCH];
  __shared__ float2 tw[256];
  init_tw(tw);
  const int li = blockIdx.x >> 5;
  const int U0 = (blockIdx.x & 31) * ROWS;
  const int img = img0 + li;
  load_complex(lds, Wb + (size_t)li * FN * FN + (size_t)U0 * FN, true /*bitrev placement for DIT*/);
  fft_dit<true>(lds, tw);
  float4* __restrict__ o4 = (float4*)(out + (size_t)img * FN * FN + (size_t)U0 * FN);
  const float sc = 1.0f / 512.0f;
  #pragma unroll
  for (int k = 0; k < 8; ++k) {
    int q = threadIdx.x + k * TPB;
    int f = q << 2;
    int row = f >> 9;
    int col = f & 511;
    float2 a = lds[row][col];
    float2 b = lds[row][col + 1];
    float2 c = lds[row][col + 2];
    float2 d = lds[row][col + 3];
    o4[q] = make_float4(sqrtf(a.x * a.x + a.y * a.y) * sc,
                        sqrtf(b.x * b.x + b.y * b.y) * sc,
                        sqrtf(c.x * c.x + c.y * c.y) * sc,
                        sqrtf(d.x * d.x + d.y * d.y) * sc);
  }
}

extern "C" void kernel_launch(void* const* d_in, const int* in_sizes, int n_in,
                              void* d_out, int out_size, void* d_ws, size_t ws_size,
                              hipStream_t stream) {
  const float* x = (const float*)d_in[0];
  float* out = (float*)d_out;
  char* ws = (char*)d_ws;

  size_t off = 0;
  ull* bins = (ull*)(ws + off);
  off += ((size_t)NBATCH * NBINS * sizeof(ull) + 255) & ~(size_t)255;
  int* cut = (int*)(ws + off);
  off += 256;
  float2* W1p = (float2*)(ws + off);
  off += (size_t)NBATCH * FN * FN * sizeof(float2);   // 16 MiB

  const size_t per_img = (size_t)FN * FN * sizeof(float2);  // 2 MiB
  size_t avail = (ws_size > off) ? (ws_size - off) : 0;
  int K = (int)(avail / (2 * per_img));
  if (K > NIMG) K = NIMG;
  if (K < 1) K = 1;
  float2* WA = (float2*)(ws + off);
  float2* WB = (float2*)(ws + off + (size_t)K * per_img);

  hipMemsetAsync(bins, 0, (size_t)NBATCH * NBINS * sizeof(ull), stream);

  // Pre-pass on the 8 channel-0 images: forward 2D FFT + ring energies + cutoffs.
  hipLaunchKernelGGL(k_fwd_real, dim3(NBATCH * 32), dim3(TPB), 0, stream, x, W1p, 0, NCH);
  hipLaunchKernelGGL(k_ring,     dim3(NBATCH * 32), dim3(TPB), 0, stream, W1p, bins);
  hipLaunchKernelGGL(k_cutoff,   dim3(1),           dim3(64),  0, stream, bins, cut);

  // Main pipeline, chunked to fit workspace.
  for (int c0 = 0; c0 < NIMG; c0 += K) {
    int nk = (NIMG - c0 < K) ? (NIMG - c0) : K;
    hipLaunchKernelGGL(k_fwd_real, dim3(nk * 32), dim3(TPB), 0, stream, x, WA, c0, 1);
    hipLaunchKernelGGL(k_mask,     dim3(nk * 32), dim3(TPB), 0, stream, WA, WB, cut, c0);
    hipLaunchKernelGGL(k_inv_abs,  dim3(nk * 32), dim3(TPB), 0, stream, WB, out, c0);
  }
}

// Round 3
// 636.123 us; speedup vs baseline: 1.8639x; 1.8639x over previous
//
#include <hip/hip_runtime.h>
#include <math.h>

#define FN 512
#define TPB 256
#define NIMG 256
#define NBATCH 8
#define NCH 32
#define NBINS 257
#define SPITCH 516   // staging row pitch (complex); byte stride 4128 -> +8 bank stagger per row

typedef unsigned long long ull;

__device__ __forceinline__ float2 cadd(float2 a, float2 b) { return make_float2(a.x + b.x, a.y + b.y); }
__device__ __forceinline__ float2 csub(float2 a, float2 b) { return make_float2(a.x - b.x, a.y - b.y); }
__device__ __forceinline__ float2 cmul(float2 a, float2 b) {
  return make_float2(fmaf(a.x, b.x, -a.y * b.y), fmaf(a.x, b.y, a.y * b.x));
}
__device__ __forceinline__ float2 cexpm(float ang) {
  float s, c;
  __sincosf(ang, &s, &c);
  return make_float2(c, s);
}
// multiply by -i (fwd) / +i (inv)
template<bool INV>
__device__ __forceinline__ float2 mulpmi(float2 a) {
  return INV ? make_float2(-a.y, a.x) : make_float2(a.y, -a.x);
}

// natural-order 8-point DFT in registers; INV=conjugate kernel (no 1/8)
template<bool INV>
__device__ __forceinline__ void dft8(float2 r[8]) {
  const float C = 0.70710678118654752440f;
  float2 t0 = cadd(r[0], r[4]), t1 = csub(r[0], r[4]);
  float2 t2 = cadd(r[2], r[6]), t3 = mulpmi<INV>(csub(r[2], r[6]));
  float2 E0 = cadd(t0, t2), E1 = cadd(t1, t3), E2 = csub(t0, t2), E3 = csub(t1, t3);
  float2 u0 = cadd(r[1], r[5]), u1 = csub(r[1], r[5]);
  float2 u2 = cadd(r[3], r[7]), u3 = mulpmi<INV>(csub(r[3], r[7]));
  float2 O0 = cadd(u0, u2), O1 = cadd(u1, u3), O2 = csub(u0, u2), O3 = csub(u1, u3);
  float2 O1w, O2w, O3w;
  if (!INV) {
    O1w = make_float2(C * (O1.x + O1.y), C * (O1.y - O1.x));   // *w8^1
    O2w = make_float2(O2.y, -O2.x);                            // *-i
    O3w = make_float2(C * (O3.y - O3.x), -C * (O3.x + O3.y));  // *w8^3
  } else {
    O1w = make_float2(C * (O1.x - O1.y), C * (O1.y + O1.x));
    O2w = make_float2(-O2.y, O2.x);
    O3w = make_float2(-C * (O3.x + O3.y), C * (O3.x - O3.y));
  }
  r[0] = cadd(E0, O0); r[1] = cadd(E1, O1w); r[2] = cadd(E2, O2w); r[3] = cadd(E3, O3w);
  r[4] = csub(E0, O0); r[5] = csub(E1, O1w); r[6] = csub(E2, O2w); r[7] = csub(E3, O3w);
}

// LDS exchange swizzle: XOR the 64-block digit into bits [3:0] -> all 4 exchange
// patterns become conflict-free (<=2 lanes/bank). Bijective within each 512 block.
__device__ __forceinline__ int swz(int q) {
  int b = (q >> 6) & 7;
  return q ^ b ^ ((b & 4) << 1);
}

#define TWOPI 6.2831853071795864769f

// 512-pt FFT, natural input (reg j = x[t+64j]) -> digit-reversed output:
// reg f = X[64f + 8(t&7) + (t>>3)]. INV=false: DFT; INV=true: 512*IDFT.
// L = this wave's private 512-complex exchange region. All LDS ops wave-internal
// (per-wave in-order DS pipe) -> no barriers.
template<bool INV>
__device__ __forceinline__ void fft512_dif(float2 r[8], float2* __restrict__ L, int t) {
  const float SG = INV ? TWOPI : -TWOPI;
  dft8<INV>(r);
  {
    float2 w1 = cexpm(SG * (float)t * (1.0f / 512.0f));
    float2 w = w1;
    #pragma unroll
    for (int k = 1; k < 8; ++k) { r[k] = cmul(r[k], w); w = cmul(w, w1); }
  }
  #pragma unroll
  for (int k = 0; k < 8; ++k) L[swz(64 * k + t)] = r[k];
  {
    const int base = 64 * (t >> 3) + (t & 7);
    #pragma unroll
    for (int d = 0; d < 8; ++d) r[d] = L[swz(base + 8 * d)];
  }
  dft8<INV>(r);
  {
    float2 w1 = cexpm(SG * (float)(t & 7) * (1.0f / 64.0f));
    float2 w = w1;
    #pragma unroll
    for (int e = 1; e < 8; ++e) { r[e] = cmul(r[e], w); w = cmul(w, w1); }
  }
  {
    const int base = 64 * (t >> 3) + (t & 7);
    #pragma unroll
    for (int e = 0; e < 8; ++e) L[swz(base + 8 * e)] = r[e];
  }
  #pragma unroll
  for (int m = 0; m < 8; ++m) r[m] = L[swz(8 * t + m)];
  dft8<INV>(r);
}

// Mirror (DIT): digit-reversed input (reg f = X[64f + 8(t&7) + (t>>3)]) -> natural
// output (reg j = x[t+64j]). INV=true gives 512*IDFT.
template<bool INV>
__device__ __forceinline__ void fft512_dit(float2 r[8], float2* __restrict__ L, int t) {
  const float SG = INV ? TWOPI : -TWOPI;
  dft8<INV>(r);  // over f -> reg c
  {
    float2 w1 = cexpm(SG * (float)(t & 7) * (1.0f / 64.0f));  // W64^{-+e}
    float2 w = w1;
    #pragma unroll
    for (int c = 1; c < 8; ++c) { r[c] = cmul(r[c], w); w = cmul(w, w1); }
  }
  #pragma unroll
  for (int c = 0; c < 8; ++c) L[swz(8 * t + c)] = r[c];
  {
    const int base = 64 * (t >> 3) + (t & 7);
    #pragma unroll
    for (int e = 0; e < 8; ++e) r[e] = L[swz(base + 8 * e)];
  }
  dft8<INV>(r);  // over e -> reg d
  {
    const int k = t >> 3, c = t & 7;
    float2 w = cexpm(SG * (float)(c * k) * (1.0f / 512.0f));
    float2 st = cexpm(SG * (float)k * (1.0f / 64.0f));
    #pragma unroll
    for (int d = 0; d < 8; ++d) { r[d] = cmul(r[d], w); w = cmul(w, st); }
  }
  {
    const int base = 64 * (t >> 3) + (t & 7);
    #pragma unroll
    for (int d = 0; d < 8; ++d) L[swz(base + 8 * d)] = r[d];
  }
  #pragma unroll
  for (int j = 0; j < 8; ++j) r[j] = L[swz(64 * j + t)];
  dft8<INV>(r);  // over k -> reg j (natural)
}

__device__ __forceinline__ int ringc(int u) { return (u < 256) ? (u + 1) : (512 - u); }

// Pass 1 (and pre-pass): real rows -> forward FFT -> transposed store W[u][r] (natural u).
__global__ __launch_bounds__(TPB) void k_fwd_real(const float* __restrict__ x,
                                                  float2* __restrict__ W,
                                                  int img0, int img_stride) {
  __shared__ float2 stg[8][SPITCH];
  const int g = threadIdx.x >> 6, t = threadIdx.x & 63;
  const int li = blockIdx.x >> 6;
  const int R0 = (blockIdx.x & 63) * 8;
  const int img = img0 + li * img_stride;
  const float* __restrict__ base = x + (size_t)img * (FN * FN);
  #pragma unroll
  for (int s = 0; s < 2; ++s) {
    const int rl = 4 * s + g;
    const float* __restrict__ row = base + (size_t)(R0 + rl) * FN;
    float2 r[8];
    #pragma unroll
    for (int j = 0; j < 8; ++j) r[j] = make_float2(row[t + 64 * j], 0.0f);
    fft512_dif<false>(r, &stg[rl][0], t);
    #pragma unroll
    for (int f = 0; f < 8; ++f) stg[rl][64 * f + 8 * (t & 7) + (t >> 3)] = r[f];
  }
  __syncthreads();
  float2* __restrict__ dst = W + (size_t)li * (FN * FN);
  const int rl2 = threadIdx.x & 3;
  const int ug0 = threadIdx.x >> 2;
  #pragma unroll
  for (int k = 0; k < 8; ++k) {
    int u = ug0 + 64 * k;
    float2 a = stg[2 * rl2][u];
    float2 b = stg[2 * rl2 + 1][u];
    float4* d4 = (float4*)(dst + (size_t)u * FN + R0);
    d4[rl2] = make_float4(a.x, a.y, b.x, b.y);
  }
}

// Pre-pass 2: FFT along h on channel-0 spectra rows; bin |F|^2 into rings (fixed-point).
__global__ __launch_bounds__(TPB) void k_ring(const float2* __restrict__ W1p, ull* __restrict__ bins) {
  __shared__ float2 ex[4][FN];
  __shared__ ull lbins[NBINS];
  const int g = threadIdx.x >> 6, t = threadIdx.x & 63;
  for (int i = threadIdx.x; i < NBINS; i += TPB) lbins[i] = 0;
  __syncthreads();
  const int li = blockIdx.x >> 6;
  const int V0 = (blockIdx.x & 63) * 8;
  const float2* __restrict__ src = W1p + (size_t)li * (FN * FN);
  #pragma unroll
  for (int s = 0; s < 2; ++s) {
    const int uw = V0 + 4 * s + g;
    const float2* __restrict__ row = src + (size_t)uw * FN;
    float2 r[8];
    #pragma unroll
    for (int j = 0; j < 8; ++j) r[j] = row[t + 64 * j];
    fft512_dif<false>(r, &ex[g][0], t);
    const int cw = ringc(uw);
    #pragma unroll
    for (int f = 0; f < 8; ++f) {
      int uh = 64 * f + 8 * (t & 7) + (t >> 3);
      int sr = max(cw, ringc(uh));
      float e = fmaf(r[f].x, r[f].x, r[f].y * r[f].y);
      atomicAdd(&lbins[sr], (ull)((double)e * 1048576.0));
    }
  }
  __syncthreads();
  for (int i = threadIdx.x; i < NBINS; i += TPB)
    if (lbins[i]) atomicAdd(&bins[(size_t)li * NBINS + i], lbins[i]);
}

__global__ __launch_bounds__(64) void k_cutoff(const ull* __restrict__ bins, int* __restrict__ cut) {
  int b = threadIdx.x;
  if (b >= NBATCH) return;
  double tot = 0.0;
  for (int r = 0; r < NBINS; ++r) tot += (double)bins[b * NBINS + r];
  double target = 0.5 * tot;
  double cum = 0.0;
  int c = 5;
  bool found = false;
  for (int r = 0; r <= 255; ++r) {
    cum += (double)bins[b * NBINS + r];
    if (r >= 1 && !found && cum >= target) { c = r; found = true; }
  }
  cut[b] = c;
}

// Pass 2: fwd FFT along h -> mask in registers -> inverse FFT -> transposed store Wb[h][uw].
__global__ __launch_bounds__(TPB) void k_mask(const float2* __restrict__ Wa, float2* __restrict__ Wb,
                                              const int* __restrict__ cut, int img0) {
  __shared__ float2 stg[8][SPITCH];
  const int g = threadIdx.x >> 6, t = threadIdx.x & 63;
  const int li = blockIdx.x >> 6;
  const int V0 = (blockIdx.x & 63) * 8;
  const int img = img0 + li;
  const int cutoff = cut[img >> 5];
  const float2* __restrict__ src = Wa + (size_t)li * (FN * FN);
  #pragma unroll
  for (int s = 0; s < 2; ++s) {
    const int rl = 4 * s + g;
    const int uw = V0 + rl;
    const float2* __restrict__ row = src + (size_t)uw * FN;
    float2 r[8];
    #pragma unroll
    for (int j = 0; j < 8; ++j) r[j] = row[t + 64 * j];
    float2* L = &stg[rl][0];
    fft512_dif<false>(r, L, t);
    const int cw = ringc(uw);
    #pragma unroll
    for (int f = 0; f < 8; ++f) {
      int uh = 64 * f + 8 * (t & 7) + (t >> 3);
      float m = (max(cw, ringc(uh)) > cutoff) ? (1.0f / 512.0f) : 0.0f;  // fold axis 1/N
      r[f].x *= m; r[f].y *= m;
    }
    fft512_dit<true>(r, L, t);
    #pragma unroll
    for (int j = 0; j < 8; ++j) stg[rl][t + 64 * j] = r[j];
  }
  __syncthreads();
  float2* __restrict__ dst = Wb + (size_t)li * (FN * FN);
  const int rl2 = threadIdx.x & 3;
  const int ug0 = threadIdx.x >> 2;
  #pragma unroll
  for (int k = 0; k < 8; ++k) {
    int n = ug0 + 64 * k;
    float2 a = stg[2 * rl2][n];
    float2 b = stg[2 * rl2 + 1][n];
    float4* d4 = (float4*)(dst + (size_t)n * FN + V0);
    d4[rl2] = make_float4(a.x, a.y, b.x, b.y);
  }
}

// Pass 3: inverse FFT along w -> |y|/512 -> direct store (digit-rev positions, coalesced 256B).
__global__ __launch_bounds__(TPB) void k_inv_abs(const float2* __restrict__ Wb, float* __restrict__ out,
                                                 int img0) {
  __shared__ float2 ex[4][FN];
  const int g = threadIdx.x >> 6, t = threadIdx.x & 63;
  const int li = blockIdx.x >> 6;
  const int H0 = (blockIdx.x & 63) * 8;
  const int img = img0 + li;
  const float2* __restrict__ src = Wb + (size_t)li * (FN * FN);
  float* __restrict__ obase = out + (size_t)img * (FN * FN);
  #pragma unroll
  for (int s = 0; s < 2; ++s) {
    const int h = H0 + 4 * s + g;
    const float2* __restrict__ row = src + (size_t)h * FN;
    float2 r[8];
    #pragma unroll
    for (int j = 0; j < 8; ++j) r[j] = row[t + 64 * j];
    fft512_dif<true>(r, &ex[g][0], t);
    float* __restrict__ orow = obase + (size_t)h * FN;
    const float sc = 1.0f / 512.0f;
    #pragma unroll
    for (int f = 0; f < 8; ++f) {
      int p = 64 * f + 8 * (t & 7) + (t >> 3);
      orow[p] = sqrtf(fmaf(r[f].x, r[f].x, r[f].y * r[f].y)) * sc;
    }
  }
}

extern "C" void kernel_launch(void* const* d_in, const int* in_sizes, int n_in,
                              void* d_out, int out_size, void* d_ws, size_t ws_size,
                              hipStream_t stream) {
  const float* x = (const float*)d_in[0];
  float* out = (float*)d_out;
  char* ws = (char*)d_ws;

  size_t off = 0;
  ull* bins = (ull*)(ws + off);
  off += ((size_t)NBATCH * NBINS * sizeof(ull) + 255) & ~(size_t)255;
  int* cut = (int*)(ws + off);
  off += 256;
  float2* W1p = (float2*)(ws + off);
  off += (size_t)NBATCH * FN * FN * sizeof(float2);  // 16 MiB

  const size_t per_img = (size_t)FN * FN * sizeof(float2);  // 2 MiB
  size_t avail = (ws_size > off) ? (ws_size - off) : 0;
  int K = (int)(avail / (2 * per_img));
  if (K > 32) K = 32;  // keep WA+WB L3-resident
  if (K < 1) K = 1;
  float2* WA = (float2*)(ws + off);
  float2* WB = (float2*)(ws + off + (size_t)K * per_img);

  hipMemsetAsync(bins, 0, (size_t)NBATCH * NBINS * sizeof(ull), stream);

  // Pre-pass on the 8 channel-0 images: forward 2D FFT + ring energies + cutoffs.
  hipLaunchKernelGGL(k_fwd_real, dim3(NBATCH * 64), dim3(TPB), 0, stream, x, W1p, 0, NCH);
  hipLaunchKernelGGL(k_ring,     dim3(NBATCH * 64), dim3(TPB), 0, stream, W1p, bins);
  hipLaunchKernelGGL(k_cutoff,   dim3(1),           dim3(64),  0, stream, bins, cut);

  // Main pipeline, chunked to fit workspace / L3.
  for (int c0 = 0; c0 < NIMG; c0 += K) {
    int nk = (NIMG - c0 < K) ? (NIMG - c0) : K;
    hipLaunchKernelGGL(k_fwd_real, dim3(nk * 64), dim3(TPB), 0, stream, x, WA, c0, 1);
    hipLaunchKernelGGL(k_mask,     dim3(nk * 64), dim3(TPB), 0, stream, WA, WB, cut, c0);
    hipLaunchKernelGGL(k_inv_abs,  dim3(nk * 64), dim3(TPB), 0, stream, WB, out, c0);
  }
}